// Round 18
// baseline (99.328 us; speedup 1.0000x reference)
//
#include <hip/hip_runtime.h>
#include <hip/hip_bf16.h>
#include <cstddef>
#include <cstdint>

// Problem constants (fixed by the reference setup)
#define N_B   8
#define L_L   4096
#define S_S   4096
#define H_H   8
#define D_D   64
#define NH    64          // N_B * H_H
// KV_aug layout (d-major): rows 0..63 = KV[d][v] (stride 68, cols 64..67 pad),
// row 64 = K_sum[d] (indexed by d in cols 0..63). KVSZ floats per (n,h).
#define KVLD  68
#define KVSZ  (65 * KVLD)   // 4420

typedef const float __attribute__((address_space(1)))* gas_fp;
typedef float __attribute__((address_space(3)))* las_fp;

__device__ __forceinline__ float elu1(float x) {
    // elu(x)+1 : x>0 ? x+1 : exp(x)
    return x > 0.f ? x + 1.f : __expf(x);
}

// ---------------------------------------------------------------------------
// Phase 1 (v13): v12's pinned pipeline at doubled occupancy.
//  v12 ledger: 60us, NO spill (VGPR 88, FETCH 66MB) — pipelining finally
//  works at the 256-reg tier with sched_barrier-pinned regions. But LDS
//  50KB + split=8 left 2 blocks/CU = 2 waves/SIMD (Occ 17.5%): nothing to
//  fill the serial region gaps; LDS-pipe floor is ~22us.
//  v13: TILE 64->32 rows -> LDS 25.6KB (6-block LDS limit); at ~88 VGPRs the
//  HW runs 4 waves/SIMD; split=16 -> 1024 blocks = exactly 4 resident
//  blocks/CU, no tail. Same schedule per 32-row tile: issue V(t+1) DMA
//  (2 chunks, no regs) + K(t+1) into 8 HELD regs | sched_barrier |
//  compute(t) | sched_barrier | vmcnt(0) + elu + lane-linear store K(t+1).
//  launch_bounds(256,2) keeps the relaxed reg cap (residency comes from
//  actual regs/LDS, not the declared minimum). Zero block barriers in loop.
// ---------------------------------------------------------------------------
__global__ __launch_bounds__(256, 2)
void la_phase1(const float* __restrict__ Kin, const float* __restrict__ Vin,
               float* __restrict__ partials, int split, int schunk)
{
    __shared__ union {
        struct { float K[32 * 64]; float V[2][32 * 64]; } st;  // 24 KB
        float acc[64 * 68];                                    // 17.3 KB
    } sm;
    __shared__ float sKsumP[4 * 64];     // per-wave ksum partials

    const int b     = blockIdx.x;
    const int nh    = b / split;
    const int chunk = b - nh * split;
    const int n     = nh >> 3;
    const int h     = nh & 7;
    const int s0    = chunk * schunk;

    const int tid  = threadIdx.x;
    const int w    = tid >> 6;
    const int lane = tid & 63;
    const int dg   = lane >> 3;   // d-group: d = dg*8 + i
    const int vg   = lane & 7;    // v-group: v = vg*8 + j

    float acc[8][8];
    #pragma unroll
    for (int i = 0; i < 8; ++i)
        #pragma unroll
        for (int j = 0; j < 8; ++j) acc[i][j] = 0.f;
    float ksum = 0.f;

    const int kd = lane;               // ksum d index (per-wave full coverage)

    // staging map: chunk c covers rows w*8+c*4..+3; lane l -> row +(l>>4),
    // col (l&15)*4 (16B); LDS dest lane-linear (conflict-free b128 writes).
    const int lrow = lane >> 4;        // 0..3
    const int lcol = (lane & 15) * 4;  // float col

    const float* Kb = Kin + (size_t)n * S_S * (H_H * D_D) + h * D_D;
    const float* Vb = Vin + (size_t)n * S_S * (H_H * D_D) + h * D_D;

    const int ntiles = schunk >> 5;    // tiles of 32 s-rows (8 at split=16)

    float4 ka0, ka1;                   // held K prefetch (8 regs)

#define ELU4(X) do { X.x = elu1(X.x); X.y = elu1(X.y); \
                     X.z = elu1(X.z); X.w = elu1(X.w); } while (0)

    // ---- prologue: tile 0 ----
    {
        #pragma unroll
        for (int c = 0; c < 2; ++c) {
            __builtin_amdgcn_global_load_lds(
                (gas_fp)(Vb + (size_t)(s0 + w * 8 + c * 4 + lrow) * (H_H * D_D) + lcol),
                (las_fp)&sm.st.V[0][(w * 8 + c * 4) * 64], 16, 0, 0);
        }
        ka0 = *(const float4*)(Kb + (size_t)(s0 + w * 8 + 0 + lrow) * (H_H * D_D) + lcol);
        ka1 = *(const float4*)(Kb + (size_t)(s0 + w * 8 + 4 + lrow) * (H_H * D_D) + lcol);
        asm volatile("s_waitcnt vmcnt(0)" ::: "memory");
        ELU4(ka0); ELU4(ka1);
        *(float4*)&sm.st.K[(w * 8 + 0) * 64 + lane * 4] = ka0;
        *(float4*)&sm.st.K[(w * 8 + 4) * 64 + lane * 4] = ka1;
    }

    for (int t = 0; t < ntiles; ++t) {
        const bool more = (t + 1 < ntiles);

        // ---- region 1: issue tile t+1 (V DMA, no regs; K into held regs) ----
        if (more) {
            const int srn = s0 + (t + 1) * 32;
            float* vdst = sm.st.V[(t + 1) & 1];
            #pragma unroll
            for (int c = 0; c < 2; ++c) {
                __builtin_amdgcn_global_load_lds(
                    (gas_fp)(Vb + (size_t)(srn + w * 8 + c * 4 + lrow) * (H_H * D_D) + lcol),
                    (las_fp)&vdst[(w * 8 + c * 4) * 64], 16, 0, 0);
            }
            ka0 = *(const float4*)(Kb + (size_t)(srn + w * 8 + 0 + lrow) * (H_H * D_D) + lcol);
            ka1 = *(const float4*)(Kb + (size_t)(srn + w * 8 + 4 + lrow) * (H_H * D_D) + lcol);
        }
        __builtin_amdgcn_sched_barrier(0);   // pin: issue | compute

        // ---- region 2: compute tile t (covers the in-flight loads) ----
        {
            const float* Kbuf = sm.st.K;
            const float* Vbuf = sm.st.V[t & 1];
            #pragma unroll
            for (int sl = 0; sl < 8; ++sl) {
                const int s = w * 8 + sl;
                const float4 k0 = *(const float4*)&Kbuf[s * 64 + dg * 8];
                const float4 k1 = *(const float4*)&Kbuf[s * 64 + dg * 8 + 4];
                const float4 v0 = *(const float4*)&Vbuf[s * 64 + vg * 8];
                const float4 v1 = *(const float4*)&Vbuf[s * 64 + vg * 8 + 4];
                const float kf[8] = {k0.x, k0.y, k0.z, k0.w, k1.x, k1.y, k1.z, k1.w};
                const float vf[8] = {v0.x, v0.y, v0.z, v0.w, v1.x, v1.y, v1.z, v1.w};
                #pragma unroll
                for (int i = 0; i < 8; ++i)
                    #pragma unroll
                    for (int j = 0; j < 8; ++j)
                        acc[i][j] = fmaf(kf[i], vf[j], acc[i][j]);
            }
            #pragma unroll
            for (int sl = 0; sl < 8; ++sl)
                ksum += Kbuf[(w * 8 + sl) * 64 + kd];
        }
        __builtin_amdgcn_sched_barrier(0);   // pin: compute | drain+store

        // ---- region 3: drain (loads covered by compute), elu, store K(t+1) ----
        if (more) {
            asm volatile("s_waitcnt vmcnt(0)" ::: "memory");
            ELU4(ka0); ELU4(ka1);
            *(float4*)&sm.st.K[(w * 8 + 0) * 64 + lane * 4] = ka0;
            *(float4*)&sm.st.K[(w * 8 + 4) * 64 + lane * 4] = ka1;
        }
    }
#undef ELU4

    __syncthreads();   // loop done (implicit full drain); sm.acc (union) safe

    // cross-wave reduce of acc into sm.acc[d][v] (stride 68), sequential & exact
    for (int ww = 0; ww < 4; ++ww) {
        if (w == ww) {
            #pragma unroll
            for (int i = 0; i < 8; ++i) {
                float* p = &sm.acc[(dg * 8 + i) * 68 + vg * 8];
                if (ww == 0) {
                    *(float4*)p       = make_float4(acc[i][0], acc[i][1], acc[i][2], acc[i][3]);
                    *(float4*)(p + 4) = make_float4(acc[i][4], acc[i][5], acc[i][6], acc[i][7]);
                } else {
                    float4 a0 = *(const float4*)p;
                    float4 a1 = *(const float4*)(p + 4);
                    a0.x += acc[i][0]; a0.y += acc[i][1]; a0.z += acc[i][2]; a0.w += acc[i][3];
                    a1.x += acc[i][4]; a1.y += acc[i][5]; a1.z += acc[i][6]; a1.w += acc[i][7];
                    *(float4*)p       = a0;
                    *(float4*)(p + 4) = a1;
                }
            }
        }
        __syncthreads();
    }

    // ksum: deterministic 4-way reduce (one slot per (wave, d))
    sKsumP[w * 64 + kd] = ksum;
    __syncthreads();

    // write this block's partial KV_aug[65][68] d-major (row 64 = K_sum, pads 0)
    float* outp = partials + (size_t)b * KVSZ;
    for (int idx = tid; idx < KVSZ; idx += 256) {
        const int r = idx / KVLD;
        const int c = idx - r * KVLD;
        float val = 0.f;
        if (c < 64) {
            if (r < 64)
                val = sm.acc[idx];   // sm.acc is [d][v] stride 68 == same layout
            else
                val = sKsumP[c] + sKsumP[64 + c] + sKsumP[128 + c] + sKsumP[192 + c];
        }
        outp[idx] = val;
    }
}

// ---------------------------------------------------------------------------
// Reduce: sum the `split` partials per (n,h) -> kvt[nh][65][68]
// ---------------------------------------------------------------------------
__global__ __launch_bounds__(256)
void la_reduce(const float* __restrict__ partials, float* __restrict__ kvt, int split)
{
    const int idx = blockIdx.x * 256 + threadIdx.x;
    if (idx >= NH * KVSZ) return;
    const int nh  = idx / KVSZ;
    const int rem = idx - nh * KVSZ;
    const float* p = partials + (size_t)nh * split * KVSZ + rem;
    float s = 0.f;
    for (int c = 0; c < split; ++c) s += p[(size_t)c * KVSZ];
    kvt[idx] = s;
}

// ---------------------------------------------------------------------------
// Phase 2 (v5): register-tiled GEMM, Out[4096][65] = Qf[4096][64]*KV[64][65].
//  Per wave 64 rows x 32 cols, lane owns 8x4 tile; per k-chunk(4): 13
//  ds_read_b128 feed 160 FMAs; KV reused 8x, Q 4x in registers. Denominator
//  = KV row 64, accumulated per-lane for its own rows. Direct global stores.
//  (Round-6 measured ~20us ~= its 21us HBM floor -> unchanged.)
// ---------------------------------------------------------------------------
__global__ __launch_bounds__(256, 2)
void la_phase2(const float* __restrict__ Qin, const float* __restrict__ kvt,
               float* __restrict__ Out)
{
    __shared__ float sQ[128 * 68];   // 34.8 KB, row-major, stride 68
    __shared__ float sKV[KVSZ];      // 17.3 KB, [65][68] d-major

    const int b   = blockIdx.x;
    const int nh  = b >> 5;          // 32 l-chunks of 128 rows per (n,h)
    const int lc  = b & 31;
    const int n   = nh >> 3;
    const int h   = nh & 7;
    const int tid = threadIdx.x;
    const int w    = tid >> 6;
    const int lane = tid & 63;

    const float* Qc = Qin + (((size_t)n * L_L + (size_t)lc * 128) * H_H + h) * D_D;
    float*       Oc = Out + (((size_t)n * L_L + (size_t)lc * 128) * H_H + h) * D_D;

    // ---- stage KV_aug[65][68] into LDS (1105 float4, coalesced) ----
    {
        const float4* src = (const float4*)(kvt + (size_t)nh * KVSZ);
        float4*       dst = (float4*)sKV;
        #pragma unroll
        for (int it = 0; it < 4; ++it)
            dst[it * 256 + tid] = src[it * 256 + tid];
        if (tid < 81) dst[1024 + tid] = src[1024 + tid];
    }

    // ---- stage Q tile 128 rows x 64 cols (elu applied), stride 68 ----
    #pragma unroll
    for (int it = 0; it < 8; ++it) {
        const int slot = it * 256 + tid;   // 0..2047
        const int r    = slot >> 4;        // 0..127
        const int c4   = slot & 15;
        float4 v = *(const float4*)(Qc + (size_t)r * (H_H * D_D) + c4 * 4);
        v.x = elu1(v.x); v.y = elu1(v.y); v.z = elu1(v.z); v.w = elu1(v.w);
        *(float4*)&sQ[r * 68 + c4 * 4] = v;
    }
    __syncthreads();

    // ---- wave work assignment ----
    const int rt   = (w >> 1) * 64;        // row tile: 0 or 64
    const int wc   = w & 1;                // col half: 0 or 1
    const int rl   = lane & 7;             // row lane: rows rt + rl + 8j
    const int cg   = lane >> 3;            // col group
    const int ccol = wc * 32 + cg * 4;     // this lane's 4 output cols

    float acc[8][4];
    float den[8];
    #pragma unroll
    for (int j = 0; j < 8; ++j) {
        den[j] = 0.f;
        #pragma unroll
        for (int m = 0; m < 4; ++m) acc[j][m] = 0.f;
    }

    const int qbase = rt + rl;             // + 8j, stride-68 rows

    for (int kc = 0; kc < 16; ++kc) {
        // Q fragments: 8 rows x 4 k  (conflict-free b128: banks partition)
        float4 qv[8];
        #pragma unroll
        for (int j = 0; j < 8; ++j)
            qv[j] = *(const float4*)&sQ[(qbase + 8 * j) * 68 + kc * 4];
        // KV fragments: 4 k-rows x lane's 4 cols (conflict-free)
        const float4 kv0 = *(const float4*)&sKV[(kc * 4 + 0) * KVLD + ccol];
        const float4 kv1 = *(const float4*)&sKV[(kc * 4 + 1) * KVLD + ccol];
        const float4 kv2 = *(const float4*)&sKV[(kc * 4 + 2) * KVLD + ccol];
        const float4 kv3 = *(const float4*)&sKV[(kc * 4 + 3) * KVLD + ccol];
        // K_sum fragment: wave-uniform broadcast
        const float4 ks  = *(const float4*)&sKV[64 * KVLD + kc * 4];

        #pragma unroll
        for (int j = 0; j < 8; ++j) {
            const float q0 = qv[j].x, q1 = qv[j].y, q2 = qv[j].z, q3 = qv[j].w;
            den[j] = fmaf(q0, ks.x, den[j]);
            den[j] = fmaf(q1, ks.y, den[j]);
            den[j] = fmaf(q2, ks.z, den[j]);
            den[j] = fmaf(q3, ks.w, den[j]);
            acc[j][0] = fmaf(q0, kv0.x, acc[j][0]);
            acc[j][0] = fmaf(q1, kv1.x, acc[j][0]);
            acc[j][0] = fmaf(q2, kv2.x, acc[j][0]);
            acc[j][0] = fmaf(q3, kv3.x, acc[j][0]);
            acc[j][1] = fmaf(q0, kv0.y, acc[j][1]);
            acc[j][1] = fmaf(q1, kv1.y, acc[j][1]);
            acc[j][1] = fmaf(q2, kv2.y, acc[j][1]);
            acc[j][1] = fmaf(q3, kv3.y, acc[j][1]);
            acc[j][2] = fmaf(q0, kv0.z, acc[j][2]);
            acc[j][2] = fmaf(q1, kv1.z, acc[j][2]);
            acc[j][2] = fmaf(q2, kv2.z, acc[j][2]);
            acc[j][2] = fmaf(q3, kv3.z, acc[j][2]);
            acc[j][3] = fmaf(q0, kv0.w, acc[j][3]);
            acc[j][3] = fmaf(q1, kv1.w, acc[j][3]);
            acc[j][3] = fmaf(q2, kv2.w, acc[j][3]);
            acc[j][3] = fmaf(q3, kv3.w, acc[j][3]);
        }
    }

    // ---- epilogue: scale by 1/(den+eps), direct coalesced global stores ----
    #pragma unroll
    for (int j = 0; j < 8; ++j) {
        const float rz = 1.0f / (den[j] + 1e-6f);
        *(float4*)(Oc + (size_t)(qbase + 8 * j) * (H_H * D_D) + ccol) =
            make_float4(acc[j][0] * rz, acc[j][1] * rz,
                        acc[j][2] * rz, acc[j][3] * rz);
    }
}

// ---------------------------------------------------------------------------
extern "C" void kernel_launch(void* const* d_in, const int* in_sizes, int n_in,
                              void* d_out, int out_size, void* d_ws, size_t ws_size,
                              hipStream_t stream)
{
    const float* Q = (const float*)d_in[0];
    const float* K = (const float*)d_in[1];
    const float* V = (const float*)d_in[2];
    float* out = (float*)d_out;

    // ws layout: [ kvt: NH*KVSZ floats ][ partials: NH*split*KVSZ floats ]
    float* kvt = (float*)d_ws;
    const size_t kvt_bytes = (size_t)NH * KVSZ * sizeof(float);

    int split = 16;   // 1024 blocks = exactly 4 resident blocks/CU (25.6KB LDS)
    while (split > 1 &&
           kvt_bytes + (size_t)NH * split * KVSZ * sizeof(float) > ws_size)
        split >>= 1;
    float* partials = kvt + (size_t)NH * KVSZ;
    const int schunk = S_S / split;

    la_phase1<<<NH * split, 256, 0, stream>>>(K, V, partials, split, schunk);

    const int red_blocks = (NH * KVSZ + 255) / 256;   // 1105 exactly
    la_reduce<<<red_blocks, 256, 0, stream>>>(partials, kvt, split);

    la_phase2<<<NH * (L_L / 128), 256, 0, stream>>>(Q, kvt, out);
}

// Round 19
// 80.986 us; speedup vs baseline: 1.2265x; 1.2265x over previous
//
#include <hip/hip_runtime.h>
#include <hip/hip_bf16.h>
#include <cstddef>
#include <cstdint>

// Problem constants (fixed by the reference setup)
#define N_B   8
#define L_L   4096
#define S_S   4096
#define H_H   8
#define D_D   64
#define NH    64          // N_B * H_H
// KV_aug layout (d-major): rows 0..63 = KV[d][v] (stride 68, cols 64..67 pad),
// row 64 = K_sum[d] (indexed by d in cols 0..63). KVSZ floats per (n,h).
#define KVLD  68
#define KVSZ  (65 * KVLD)   // 4420
#define ROWF  (H_H * D_D)   // 512 floats per s-row
#define TSTEP (32 * ROWF)   // floats per 32-s tile step
#define KTLD  40            // bf16 (short) row stride of transposed tiles (80 B)

typedef float f32x4 __attribute__((ext_vector_type(4)));
typedef short bf16x8 __attribute__((ext_vector_type(8)));

__device__ __forceinline__ float elu1(float x) {
    // elu(x)+1 : x>0 ? x+1 : exp(x)
    return x > 0.f ? x + 1.f : __expf(x);
}

// pack (a,b) -> bf16x2 (RNE) and store at transposed position [d][2*a2..+1]
__device__ __forceinline__ void wr_pair(short* base, int d, int a2, float a, float b) {
    *reinterpret_cast<__hip_bfloat162*>(&base[d * KTLD + 2 * a2]) =
        __float22bfloat162_rn(make_float2(a, b));
}

// ---------------------------------------------------------------------------
// Phase 1 (v14): bf16 MFMA. KV = K^T · V is a 64x64x4096 GEMM per (n,h) —
//  fp32 VALU versions plateaued at 60us latency-bound (v7-v13: no pipe >40%).
//  bf16 error analysis: incoherent accumulation over S=4096 -> out absmax
//  contribution ~6e-5 (threshold 1.17e-3; current slack ~9e-4).
//  Structure = v12's wave-private / zero-barrier / pinned regions. Per wave,
//  per 32-s tile: load K,V(t+1) -> 16 held float4 | SB | compute(t): 8
//  ds_read_b128 fragments + 16 mfma_16x16x32_bf16 (+4 vs ones-B = K_sum
//  free) | SB | elu + cvt_pk + transposed store (d-major bf16, 80B rows:
//  16B-aligned fragments). Verified C-layout (m89): col=lane&15,
//  row=(lane>>4)*4+reg drives the epilogue; kvt/reduce/phase2 unchanged.
//  split=8: 512 blocks = 2/CU at 42KB LDS, 8 waves/CU, (256,2) reg tier.
// ---------------------------------------------------------------------------
__global__ __launch_bounds__(256, 2)
void la_phase1(const float* __restrict__ Kin, const float* __restrict__ Vin,
               float* __restrict__ partials, int split, int schunk)
{
    __shared__ union {
        struct { short Kt[4][64 * KTLD]; short Vt[4][64 * KTLD]; } st; // 40.96 KB
        float acc[64 * 68];                                            // 17.4 KB
    } sm;
    __shared__ float sKsumP[4 * 64];     // per-wave ksum partials

    const int b     = blockIdx.x;
    const int nh    = b / split;
    const int chunk = b - nh * split;
    const int n     = nh >> 3;
    const int h     = nh & 7;
    const int s0    = chunk * schunk;

    const int tid  = threadIdx.x;
    const int w    = tid >> 6;
    const int lane = tid & 63;
    const int a2   = lane & 15;        // s-pair index (tile-local s = 2*a2, 2*a2+1)
    const int kg   = lane >> 4;        // k-group (0..3)
    const int dgrp = kg * 16;          // this lane stages d = dgrp..dgrp+15

    f32x4 acc[4][4];                   // 16 output tiles (m=d-tile, n=v-tile)
    f32x4 acck[4];                     // K_sum accumulator (A x ones)
    const f32x4 z4 = {0.f, 0.f, 0.f, 0.f};
    #pragma unroll
    for (int m = 0; m < 4; ++m) {
        acck[m] = z4;
        #pragma unroll
        for (int nn = 0; nn < 4; ++nn) acc[m][nn] = z4;
    }
    const bf16x8 ones = {0x3F80, 0x3F80, 0x3F80, 0x3F80,
                         0x3F80, 0x3F80, 0x3F80, 0x3F80};   // bf16 1.0 x8

    short* kt = sm.st.Kt[w];
    short* vt = sm.st.Vt[w];

    // per-lane global source pointers (advance by TSTEP per tile)
    const size_t base = (size_t)n * S_S * ROWF + h * D_D;
    const int swave   = s0 + w * (schunk >> 2) + 2 * a2;  // wave-private s-range
    const float* kpe = Kin + base + (size_t)swave * ROWF + dgrp;
    const float* kpo = kpe + ROWF;
    const float* vpe = Vin + base + (size_t)swave * ROWF + dgrp;
    const float* vpo = vpe + ROWF;

    const int ntiles = schunk >> 7;    // per-wave tiles of 32 s (4 at split=8)

    float4 kA0, kA1, kA2, kA3, kB0, kB1, kB2, kB3;
    float4 vA0, vA1, vA2, vA3, vB0, vB1, vB2, vB3;

#define LOADT()                                                              \
    do {                                                                     \
        kA0 = *(const float4*)(kpe + 0);  kA1 = *(const float4*)(kpe + 4);   \
        kA2 = *(const float4*)(kpe + 8);  kA3 = *(const float4*)(kpe + 12);  \
        kB0 = *(const float4*)(kpo + 0);  kB1 = *(const float4*)(kpo + 4);   \
        kB2 = *(const float4*)(kpo + 8);  kB3 = *(const float4*)(kpo + 12);  \
        vA0 = *(const float4*)(vpe + 0);  vA1 = *(const float4*)(vpe + 4);   \
        vA2 = *(const float4*)(vpe + 8);  vA3 = *(const float4*)(vpe + 12);  \
        vB0 = *(const float4*)(vpo + 0);  vB1 = *(const float4*)(vpo + 4);   \
        vB2 = *(const float4*)(vpo + 8);  vB3 = *(const float4*)(vpo + 12);  \
        kpe += TSTEP; kpo += TSTEP; vpe += TSTEP; vpo += TSTEP;              \
    } while (0)

#define WRITET()                                                             \
    do {                                                                     \
        wr_pair(kt, dgrp +  0, a2, elu1(kA0.x), elu1(kB0.x));                \
        wr_pair(kt, dgrp +  1, a2, elu1(kA0.y), elu1(kB0.y));                \
        wr_pair(kt, dgrp +  2, a2, elu1(kA0.z), elu1(kB0.z));                \
        wr_pair(kt, dgrp +  3, a2, elu1(kA0.w), elu1(kB0.w));                \
        wr_pair(kt, dgrp +  4, a2, elu1(kA1.x), elu1(kB1.x));                \
        wr_pair(kt, dgrp +  5, a2, elu1(kA1.y), elu1(kB1.y));                \
        wr_pair(kt, dgrp +  6, a2, elu1(kA1.z), elu1(kB1.z));                \
        wr_pair(kt, dgrp +  7, a2, elu1(kA1.w), elu1(kB1.w));                \
        wr_pair(kt, dgrp +  8, a2, elu1(kA2.x), elu1(kB2.x));                \
        wr_pair(kt, dgrp +  9, a2, elu1(kA2.y), elu1(kB2.y));                \
        wr_pair(kt, dgrp + 10, a2, elu1(kA2.z), elu1(kB2.z));                \
        wr_pair(kt, dgrp + 11, a2, elu1(kA2.w), elu1(kB2.w));                \
        wr_pair(kt, dgrp + 12, a2, elu1(kA3.x), elu1(kB3.x));                \
        wr_pair(kt, dgrp + 13, a2, elu1(kA3.y), elu1(kB3.y));                \
        wr_pair(kt, dgrp + 14, a2, elu1(kA3.z), elu1(kB3.z));                \
        wr_pair(kt, dgrp + 15, a2, elu1(kA3.w), elu1(kB3.w));                \
        wr_pair(vt, dgrp +  0, a2, vA0.x, vB0.x);                            \
        wr_pair(vt, dgrp +  1, a2, vA0.y, vB0.y);                            \
        wr_pair(vt, dgrp +  2, a2, vA0.z, vB0.z);                            \
        wr_pair(vt, dgrp +  3, a2, vA0.w, vB0.w);                            \
        wr_pair(vt, dgrp +  4, a2, vA1.x, vB1.x);                            \
        wr_pair(vt, dgrp +  5, a2, vA1.y, vB1.y);                            \
        wr_pair(vt, dgrp +  6, a2, vA1.z, vB1.z);                            \
        wr_pair(vt, dgrp +  7, a2, vA1.w, vB1.w);                            \
        wr_pair(vt, dgrp +  8, a2, vA2.x, vB2.x);                            \
        wr_pair(vt, dgrp +  9, a2, vA2.y, vB2.y);                            \
        wr_pair(vt, dgrp + 10, a2, vA2.z, vB2.z);                            \
        wr_pair(vt, dgrp + 11, a2, vA2.w, vB2.w);                            \
        wr_pair(vt, dgrp + 12, a2, vA3.x, vB3.x);                            \
        wr_pair(vt, dgrp + 13, a2, vA3.y, vB3.y);                            \
        wr_pair(vt, dgrp + 14, a2, vA3.z, vB3.z);                            \
        wr_pair(vt, dgrp + 15, a2, vA3.w, vB3.w);                            \
    } while (0)

    // ---- prologue: tile 0 staged ----
    LOADT();
    WRITET();

    for (int t = 0; t < ntiles; ++t) {
        const bool more = (t + 1 < ntiles);

        // region 1: issue tile t+1 into held regs
        if (more) LOADT();
        __builtin_amdgcn_sched_barrier(0);

        // region 2: MFMA compute on tile t (fragments from LDS)
        {
            // A-frag (K^T): row = m*16 + (lane&15) = d, k = kg*8.. (s)
            bf16x8 af0 = *(const bf16x8*)&kt[(0 * 16 + a2) * KTLD + kg * 8];
            bf16x8 af1 = *(const bf16x8*)&kt[(1 * 16 + a2) * KTLD + kg * 8];
            bf16x8 af2 = *(const bf16x8*)&kt[(2 * 16 + a2) * KTLD + kg * 8];
            bf16x8 af3 = *(const bf16x8*)&kt[(3 * 16 + a2) * KTLD + kg * 8];
            // B-frag (V): col = n*16 + (lane&15) = v, k = kg*8.. (s)
            bf16x8 bf0 = *(const bf16x8*)&vt[(0 * 16 + a2) * KTLD + kg * 8];
            bf16x8 bf1 = *(const bf16x8*)&vt[(1 * 16 + a2) * KTLD + kg * 8];
            bf16x8 bf2 = *(const bf16x8*)&vt[(2 * 16 + a2) * KTLD + kg * 8];
            bf16x8 bf3 = *(const bf16x8*)&vt[(3 * 16 + a2) * KTLD + kg * 8];

            acc[0][0] = __builtin_amdgcn_mfma_f32_16x16x32_bf16(af0, bf0, acc[0][0], 0, 0, 0);
            acc[0][1] = __builtin_amdgcn_mfma_f32_16x16x32_bf16(af0, bf1, acc[0][1], 0, 0, 0);
            acc[0][2] = __builtin_amdgcn_mfma_f32_16x16x32_bf16(af0, bf2, acc[0][2], 0, 0, 0);
            acc[0][3] = __builtin_amdgcn_mfma_f32_16x16x32_bf16(af0, bf3, acc[0][3], 0, 0, 0);
            acc[1][0] = __builtin_amdgcn_mfma_f32_16x16x32_bf16(af1, bf0, acc[1][0], 0, 0, 0);
            acc[1][1] = __builtin_amdgcn_mfma_f32_16x16x32_bf16(af1, bf1, acc[1][1], 0, 0, 0);
            acc[1][2] = __builtin_amdgcn_mfma_f32_16x16x32_bf16(af1, bf2, acc[1][2], 0, 0, 0);
            acc[1][3] = __builtin_amdgcn_mfma_f32_16x16x32_bf16(af1, bf3, acc[1][3], 0, 0, 0);
            acc[2][0] = __builtin_amdgcn_mfma_f32_16x16x32_bf16(af2, bf0, acc[2][0], 0, 0, 0);
            acc[2][1] = __builtin_amdgcn_mfma_f32_16x16x32_bf16(af2, bf1, acc[2][1], 0, 0, 0);
            acc[2][2] = __builtin_amdgcn_mfma_f32_16x16x32_bf16(af2, bf2, acc[2][2], 0, 0, 0);
            acc[2][3] = __builtin_amdgcn_mfma_f32_16x16x32_bf16(af2, bf3, acc[2][3], 0, 0, 0);
            acc[3][0] = __builtin_amdgcn_mfma_f32_16x16x32_bf16(af3, bf0, acc[3][0], 0, 0, 0);
            acc[3][1] = __builtin_amdgcn_mfma_f32_16x16x32_bf16(af3, bf1, acc[3][1], 0, 0, 0);
            acc[3][2] = __builtin_amdgcn_mfma_f32_16x16x32_bf16(af3, bf2, acc[3][2], 0, 0, 0);
            acc[3][3] = __builtin_amdgcn_mfma_f32_16x16x32_bf16(af3, bf3, acc[3][3], 0, 0, 0);
            // K_sum: A x ones -> row sums of K^T (all 16 cols identical)
            acck[0] = __builtin_amdgcn_mfma_f32_16x16x32_bf16(af0, ones, acck[0], 0, 0, 0);
            acck[1] = __builtin_amdgcn_mfma_f32_16x16x32_bf16(af1, ones, acck[1], 0, 0, 0);
            acck[2] = __builtin_amdgcn_mfma_f32_16x16x32_bf16(af2, ones, acck[2], 0, 0, 0);
            acck[3] = __builtin_amdgcn_mfma_f32_16x16x32_bf16(af3, ones, acck[3], 0, 0, 0);
        }
        __builtin_amdgcn_sched_barrier(0);

        // region 3: elu + cvt_pk + transposed store of tile t+1 (wave-private,
        // same buffer: this wave's compute(t) reads are already complete)
        if (more) WRITET();
    }
#undef LOADT
#undef WRITET

    __syncthreads();   // all waves done; sm.acc (union) safe to overwrite

    // ksum partials: lane (a2==0) of each k-group owns d = m*16 + kg*4 + r
    #pragma unroll
    for (int m = 0; m < 4; ++m)
        #pragma unroll
        for (int r = 0; r < 4; ++r)
            if (a2 == 0) sKsumP[w * 64 + m * 16 + kg * 4 + r] = acck[m][r];

    // cross-wave reduce of acc into sm.acc[d][v] (stride 68), sequential & exact
    // C/D layout (m89-verified): col = lane&15, row = (lane>>4)*4 + reg
    for (int ww = 0; ww < 4; ++ww) {
        if (w == ww) {
            #pragma unroll
            for (int m = 0; m < 4; ++m)
                #pragma unroll
                for (int nn = 0; nn < 4; ++nn)
                    #pragma unroll
                    for (int r = 0; r < 4; ++r) {
                        const int d = m * 16 + kg * 4 + r;
                        const int v = nn * 16 + a2;
                        if (ww == 0) sm.acc[d * 68 + v]  = acc[m][nn][r];
                        else         sm.acc[d * 68 + v] += acc[m][nn][r];
                    }
        }
        __syncthreads();
    }

    // write this block's partial KV_aug[65][68] d-major (row 64 = K_sum, pads 0)
    float* outp = partials + (size_t)b * KVSZ;
    for (int idx = tid; idx < KVSZ; idx += 256) {
        const int r = idx / KVLD;
        const int c = idx - r * KVLD;
        float val = 0.f;
        if (c < 64) {
            if (r < 64)
                val = sm.acc[idx];   // sm.acc is [d][v] stride 68 == same layout
            else
                val = sKsumP[c] + sKsumP[64 + c] + sKsumP[128 + c] + sKsumP[192 + c];
        }
        outp[idx] = val;
    }
}

// ---------------------------------------------------------------------------
// Reduce: sum the `split` partials per (n,h) -> kvt[nh][65][68]
// ---------------------------------------------------------------------------
__global__ __launch_bounds__(256)
void la_reduce(const float* __restrict__ partials, float* __restrict__ kvt, int split)
{
    const int idx = blockIdx.x * 256 + threadIdx.x;
    if (idx >= NH * KVSZ) return;
    const int nh  = idx / KVSZ;
    const int rem = idx - nh * KVSZ;
    const float* p = partials + (size_t)nh * split * KVSZ + rem;
    float s = 0.f;
    for (int c = 0; c < split; ++c) s += p[(size_t)c * KVSZ];
    kvt[idx] = s;
}

// ---------------------------------------------------------------------------
// Phase 2 (v5): register-tiled GEMM, Out[4096][65] = Qf[4096][64]*KV[64][65].
//  Per wave 64 rows x 32 cols, lane owns 8x4 tile; per k-chunk(4): 13
//  ds_read_b128 feed 160 FMAs; KV reused 8x, Q 4x in registers. Denominator
//  = KV row 64, accumulated per-lane for its own rows. Direct global stores.
//  (Round-6 measured ~20us ~= its 21us HBM floor -> unchanged.)
// ---------------------------------------------------------------------------
__global__ __launch_bounds__(256, 2)
void la_phase2(const float* __restrict__ Qin, const float* __restrict__ kvt,
               float* __restrict__ Out)
{
    __shared__ float sQ[128 * 68];   // 34.8 KB, row-major, stride 68
    __shared__ float sKV[KVSZ];      // 17.3 KB, [65][68] d-major

    const int b   = blockIdx.x;
    const int nh  = b >> 5;          // 32 l-chunks of 128 rows per (n,h)
    const int lc  = b & 31;
    const int n   = nh >> 3;
    const int h   = nh & 7;
    const int tid = threadIdx.x;
    const int w    = tid >> 6;
    const int lane = tid & 63;

    const float* Qc = Qin + (((size_t)n * L_L + (size_t)lc * 128) * H_H + h) * D_D;
    float*       Oc = Out + (((size_t)n * L_L + (size_t)lc * 128) * H_H + h) * D_D;

    // ---- stage KV_aug[65][68] into LDS (1105 float4, coalesced) ----
    {
        const float4* src = (const float4*)(kvt + (size_t)nh * KVSZ);
        float4*       dst = (float4*)sKV;
        #pragma unroll
        for (int it = 0; it < 4; ++it)
            dst[it * 256 + tid] = src[it * 256 + tid];
        if (tid < 81) dst[1024 + tid] = src[1024 + tid];
    }

    // ---- stage Q tile 128 rows x 64 cols (elu applied), stride 68 ----
    #pragma unroll
    for (int it = 0; it < 8; ++it) {
        const int slot = it * 256 + tid;   // 0..2047
        const int r    = slot >> 4;        // 0..127
        const int c4   = slot & 15;
        float4 v = *(const float4*)(Qc + (size_t)r * (H_H * D_D) + c4 * 4);
        v.x = elu1(v.x); v.y = elu1(v.y); v.z = elu1(v.z); v.w = elu1(v.w);
        *(float4*)&sQ[r * 68 + c4 * 4] = v;
    }
    __syncthreads();

    // ---- wave work assignment ----
    const int rt   = (w >> 1) * 64;        // row tile: 0 or 64
    const int wc   = w & 1;                // col half: 0 or 1
    const int rl   = lane & 7;             // row lane: rows rt + rl + 8j
    const int cg   = lane >> 3;            // col group
    const int ccol = wc * 32 + cg * 4;     // this lane's 4 output cols

    float acc[8][4];
    float den[8];
    #pragma unroll
    for (int j = 0; j < 8; ++j) {
        den[j] = 0.f;
        #pragma unroll
        for (int m = 0; m < 4; ++m) acc[j][m] = 0.f;
    }

    const int qbase = rt + rl;             // + 8j, stride-68 rows

    for (int kc = 0; kc < 16; ++kc) {
        // Q fragments: 8 rows x 4 k  (conflict-free b128: banks partition)
        float4 qv[8];
        #pragma unroll
        for (int j = 0; j < 8; ++j)
            qv[j] = *(const float4*)&sQ[(qbase + 8 * j) * 68 + kc * 4];
        // KV fragments: 4 k-rows x lane's 4 cols (conflict-free)
        const float4 kv0 = *(const float4*)&sKV[(kc * 4 + 0) * KVLD + ccol];
        const float4 kv1 = *(const float4*)&sKV[(kc * 4 + 1) * KVLD + ccol];
        const float4 kv2 = *(const float4*)&sKV[(kc * 4 + 2) * KVLD + ccol];
        const float4 kv3 = *(const float4*)&sKV[(kc * 4 + 3) * KVLD + ccol];
        // K_sum fragment: wave-uniform broadcast
        const float4 ks  = *(const float4*)&sKV[64 * KVLD + kc * 4];

        #pragma unroll
        for (int j = 0; j < 8; ++j) {
            const float q0 = qv[j].x, q1 = qv[j].y, q2 = qv[j].z, q3 = qv[j].w;
            den[j] = fmaf(q0, ks.x, den[j]);
            den[j] = fmaf(q1, ks.y, den[j]);
            den[j] = fmaf(q2, ks.z, den[j]);
            den[j] = fmaf(q3, ks.w, den[j]);
            acc[j][0] = fmaf(q0, kv0.x, acc[j][0]);
            acc[j][0] = fmaf(q1, kv1.x, acc[j][0]);
            acc[j][0] = fmaf(q2, kv2.x, acc[j][0]);
            acc[j][0] = fmaf(q3, kv3.x, acc[j][0]);
            acc[j][1] = fmaf(q0, kv0.y, acc[j][1]);
            acc[j][1] = fmaf(q1, kv1.y, acc[j][1]);
            acc[j][1] = fmaf(q2, kv2.y, acc[j][1]);
            acc[j][1] = fmaf(q3, kv3.y, acc[j][1]);
            acc[j][2] = fmaf(q0, kv0.z, acc[j][2]);
            acc[j][2] = fmaf(q1, kv1.z, acc[j][2]);
            acc[j][2] = fmaf(q2, kv2.z, acc[j][2]);
            acc[j][2] = fmaf(q3, kv3.z, acc[j][2]);
            acc[j][3] = fmaf(q0, kv0.w, acc[j][3]);
            acc[j][3] = fmaf(q1, kv1.w, acc[j][3]);
            acc[j][3] = fmaf(q2, kv2.w, acc[j][3]);
            acc[j][3] = fmaf(q3, kv3.w, acc[j][3]);
        }
    }

    // ---- epilogue: scale by 1/(den+eps), direct coalesced global stores ----
    #pragma unroll
    for (int j = 0; j < 8; ++j) {
        const float rz = 1.0f / (den[j] + 1e-6f);
        *(float4*)(Oc + (size_t)(qbase + 8 * j) * (H_H * D_D) + ccol) =
            make_float4(acc[j][0] * rz, acc[j][1] * rz,
                        acc[j][2] * rz, acc[j][3] * rz);
    }
}

// ---------------------------------------------------------------------------
extern "C" void kernel_launch(void* const* d_in, const int* in_sizes, int n_in,
                              void* d_out, int out_size, void* d_ws, size_t ws_size,
                              hipStream_t stream)
{
    const float* Q = (const float*)d_in[0];
    const float* K = (const float*)d_in[1];
    const float* V = (const float*)d_in[2];
    float* out = (float*)d_out;

    // ws layout: [ kvt: NH*KVSZ floats ][ partials: NH*split*KVSZ floats ]
    float* kvt = (float*)d_ws;
    const size_t kvt_bytes = (size_t)NH * KVSZ * sizeof(float);

    int split = 8;    // 512 blocks = 2 resident blocks/CU at 42KB LDS
    while (split > 1 &&
           kvt_bytes + (size_t)NH * split * KVSZ * sizeof(float) > ws_size)
        split >>= 1;
    float* partials = kvt + (size_t)NH * KVSZ;
    const int schunk = S_S / split;

    la_phase1<<<NH * split, 256, 0, stream>>>(K, V, partials, split, schunk);

    const int red_blocks = (NH * KVSZ + 255) / 256;   // 1105 exactly
    la_reduce<<<red_blocks, 256, 0, stream>>>(partials, kvt, split);

    la_phase2<<<NH * (L_L / 128), 256, 0, stream>>>(Q, kvt, out);
}